// Round 11
// baseline (32.531 us; speedup 1.0000x reference)
//
#include <hip/hip_runtime.h>
#include <hip/hip_bf16.h>

#define NUM_CAMS 6
#define NQ       40000
#define MAX_LEN  10000
#define ED       256
#define NBLK     ((NQ + 255) / 256)   // 157

typedef float f32x2 __attribute__((ext_vector_type(2)));
typedef unsigned long long u64;

// d_out layout (float offsets)
#define OFF_IDX  0                                   // 6*10000
#define OFF_LEN  (NUM_CAMS * MAX_LEN)                // 60000, size 6
#define OFF_Q    (OFF_LEN + NUM_CAMS)                // 60006 (byte 240024: 8 mod 16)
#define OFF_REF  (OFF_Q + NUM_CAMS * MAX_LEN * ED)   // 15,420,006
#define OFF_CNT  (OFF_REF + NUM_CAMS * MAX_LEN * 8)  // 15,900,006

// ws layout (ints)
#define WS_OFF    0                               // [0, 942) per-(cam,block) valid counts
#define WS_MASK_I 960                             // u64 ballot masks, byte 3840 (8B aligned)
#define WS_MASK_N (NUM_CAMS * NBLK * 4)           // 3768 u64 = 7536 ints
#define WS_LEN    (WS_MASK_I + 2 * WS_MASK_N)     // 8496, +6 per-cam len
#define WS_NEED_BYTES ((WS_LEN + 8) * 4)          // ~34 KB

#define GATHER_BLOCKS (NUM_CAMS * MAX_LEN / 4)    // 15000 (4 rows/block, row-major)

// 157 blocks: per-(block,cam) valid counts + ballot masks + fused count_norm.
__global__ void kA_counts(const int* __restrict__ bev, float* __restrict__ out,
                          int* __restrict__ ws, int useMask) {
    __shared__ int cnt[NUM_CAMS];
    const int tid = threadIdx.x;
    const int blk = blockIdx.x;
    const int q   = blk * 256 + tid;
    if (tid < NUM_CAMS) cnt[tid] = 0;
    __syncthreads();
    const int lane = tid & 63;
    const int wave = tid >> 6;
    const bool inb = q < NQ;
    u64* wsm = reinterpret_cast<u64*>(ws + WS_MASK_I);
    int myCount = 0;
    #pragma unroll
    for (int cam = 0; cam < NUM_CAMS; ++cam) {
        bool v = false;
        if (inb) {
            const int4 m = *reinterpret_cast<const int4*>(bev + ((size_t)cam * NQ + q) * 4);
            v = (m.x > 0) | (m.y > 0) | (m.z > 0) | (m.w > 0);
        }
        myCount += v ? 1 : 0;
        const u64 bal = __ballot(v);
        if (lane == 0) {
            atomicAdd(&cnt[cam], __popcll(bal));
            if (useMask) wsm[((size_t)cam * NBLK + blk) * 4 + wave] = bal;
        }
    }
    if (inb) out[OFF_CNT + q] = 1.0f / fmaxf((float)myCount, 1.0f);
    __syncthreads();
    if (tid < NUM_CAMS) ws[WS_OFF + tid * NBLK + blk] = cnt[tid];
}

// (157,6) blocks: wave-reduce partials -> exclusive offset + total; valid bits
// from stored ballot masks (no bev re-read). Writes stable-partition idx + len.
__global__ void kBC_indexes(const int* __restrict__ bev, float* __restrict__ out,
                            int* __restrict__ ws, int useMask) {
    const int blk = blockIdx.x;
    const int cam = blockIdx.y;
    const int tid = threadIdx.x;
    const int lane = tid & 63;
    const int wave = tid >> 6;

    const int part = (tid < NBLK) ? ws[WS_OFF + cam * NBLK + tid] : 0;
    int t = part;                       // total over all blocks
    int o = (tid < blk) ? part : 0;     // exclusive offset for this block
    #pragma unroll
    for (int d = 1; d < 64; d <<= 1) {
        t += __shfl_xor(t, d, 64);
        o += __shfl_xor(o, d, 64);
    }
    __shared__ int sT[4], sO[4], waveSums[4];

    u64 mask;
    if (useMask) {
        const u64* wsm = reinterpret_cast<const u64*>(ws + WS_MASK_I);
        mask = wsm[((size_t)cam * NBLK + blk) * 4 + wave];
    } else {
        const int q = blk * 256 + tid;
        bool v = false;
        if (q < NQ) {
            const int4 m = *reinterpret_cast<const int4*>(bev + ((size_t)cam * NQ + q) * 4);
            v = (m.x > 0) | (m.y > 0) | (m.z > 0) | (m.w > 0);
        }
        mask = __ballot(v);
    }
    if (lane == 0) { sT[wave] = t; sO[wave] = o; waveSums[wave] = __popcll(mask); }
    __syncthreads();
    const int total    = sT[0] + sT[1] + sT[2] + sT[3];
    const int blockOff = sO[0] + sO[1] + sO[2] + sO[3];

    if (blk == 0 && tid == 0) {
        const int len = total < MAX_LEN ? total : MAX_LEN;
        ws[WS_LEN + cam] = len;
        out[OFF_LEN + cam] = (float)len;
    }

    const int q = blk * 256 + tid;
    if (q < NQ) {
        int waveOff = 0;
        #pragma unroll
        for (int w = 0; w < 4; ++w)
            if (w < wave) waveOff += waveSums[w];
        const bool v     = (mask >> lane) & 1ull;
        const int prefix = __popcll(mask & ((1ull << lane) - 1ull));
        const int vb  = blockOff + waveOff + prefix;      // valid strictly before q
        const int pos = v ? vb : (total + (q - vb));      // stable partition position
        if (pos < MAX_LEN) out[OFF_IDX + cam * MAX_LEN + pos] = (float)q;
    }
}

// 15000 blocks, row-major over OUTPUT rows (4 rows/block, 64 lanes/row):
// sequential 1KB writes in block order (HBM-friendly streaming); reads are
// query[idx] with idx sorted increasing (near-sequential, 6x L2/L3-shared).
// Rows past len are zeroed in the same pass. Plain stores (no NT).
__global__ void kGatherRM(const float* __restrict__ query, const float* __restrict__ refp,
                          float* __restrict__ out, const int* __restrict__ ws) {
    const int rowId = blockIdx.x * 4 + (threadIdx.x >> 6);
    const int lane  = threadIdx.x & 63;
    const int cam   = rowId / MAX_LEN;
    const int j     = rowId - cam * MAX_LEN;
    const int len   = ws[WS_LEN + cam];

    f32x2 a = (f32x2)(0.f), b = (f32x2)(0.f), r0 = (f32x2)(0.f), r1 = (f32x2)(0.f);
    if (j < len) {
        const int idx = (int)out[OFF_IDX + cam * MAX_LEN + j];
        const float4 vq = *reinterpret_cast<const float4*>(query + (size_t)idx * ED + lane * 4);
        a.x = vq.x; a.y = vq.y;
        b.x = vq.z; b.y = vq.w;
        if (lane < 2) {
            const float4 r = *reinterpret_cast<const float4*>(refp + ((size_t)cam * NQ + idx) * 8 + lane * 4);
            r0.x = r.x; r0.y = r.y;
            r1.x = r.z; r1.y = r.w;
        }
    }
    f32x2* o2 = reinterpret_cast<f32x2*>(out + OFF_Q + (size_t)rowId * ED + lane * 4);
    o2[0] = a;
    o2[1] = b;
    if (lane < 2) {
        f32x2* r2 = reinterpret_cast<f32x2*>(out + OFF_REF + (size_t)rowId * 8 + lane * 4);
        r2[0] = r0;
        r2[1] = r1;
    }
}

extern "C" void kernel_launch(void* const* d_in, const int* in_sizes, int n_in,
                              void* d_out, int out_size, void* d_ws, size_t ws_size,
                              hipStream_t stream) {
    const float* query = (const float*)d_in[0];
    const float* refp  = (const float*)d_in[1];
    const int*   bev   = (const int*)d_in[2];
    float* out = (float*)d_out;
    int*   ws  = (int*)d_ws;
    const int useMask = (ws_size >= (size_t)WS_NEED_BYTES) ? 1 : 0;

    kA_counts<<<NBLK, 256, 0, stream>>>(bev, out, ws, useMask);
    kBC_indexes<<<dim3(NBLK, NUM_CAMS), 256, 0, stream>>>(bev, out, ws, useMask);
    kGatherRM<<<GATHER_BLOCKS, 256, 0, stream>>>(query, refp, out, ws);
}

// Round 12
// 30.934 us; speedup vs baseline: 1.0516x; 1.0516x over previous
//
#include <hip/hip_runtime.h>
#include <hip/hip_bf16.h>

#define NUM_CAMS 6
#define NQ       40000
#define MAX_LEN  10000
#define ED       256
#define NBLK     ((NQ + 255) / 256)   // 157

typedef float f32x2 __attribute__((ext_vector_type(2)));

// d_out layout (float offsets)
#define OFF_IDX  0                                   // 6*10000
#define OFF_LEN  (NUM_CAMS * MAX_LEN)                // 60000, size 6
#define OFF_Q    (OFF_LEN + NUM_CAMS)                // 60006
#define OFF_REF  (OFF_Q + NUM_CAMS * MAX_LEN * ED)   // 15,420,006
#define OFF_CNT  (OFF_REF + NUM_CAMS * MAX_LEN * 8)  // 15,900,006

// ws layout (ints)
#define WS_OFF    0                               // [0, 942) per-(cam,block) valid counts
#define WS_MASK_I 960                             // u64 ballot masks, byte off 3840 (8B aligned)
#define WS_MASK_N (NUM_CAMS * NBLK * 4)           // 3768 u64 = 7536 ints
#define WS_LEN    (WS_MASK_I + 2 * WS_MASK_N)     // 8496, +6 per-cam len
#define WS_POS    (WS_LEN + 8)                    // 8504, +6*NQ q->pos table
#define WS_NEED_BYTES ((WS_POS + NUM_CAMS * NQ) * 4)

#define QBLOCKS      (NQ / 4)                       // 10000 q-group items (4 q each)
#define TAIL_BLOCKS  (NUM_CAMS * MAX_LEN / 4)       // 15000 tail items (4 rows each)
#define GATHER_GRID  2048                           // persistent blocks for kGatherQ
#define CNT_BLOCKS   ((NQ + 255) / 256)             // 157 (fallback count_norm)
#define GATHER_BLOCKS (NUM_CAMS * MAX_LEN / 4)      // 15000 (fallback row-major)

// 157 blocks: per-(block,cam) valid counts + ballot masks + fused count_norm.
__global__ void kA_counts(const int* __restrict__ bev, float* __restrict__ out,
                          int* __restrict__ ws, int usePos) {
    __shared__ int cnt[NUM_CAMS];
    const int tid = threadIdx.x;
    const int blk = blockIdx.x;
    const int q   = blk * 256 + tid;
    if (tid < NUM_CAMS) cnt[tid] = 0;
    __syncthreads();
    const int lane = tid & 63;
    const int wave = tid >> 6;
    const bool inb = q < NQ;
    unsigned long long* wsm = reinterpret_cast<unsigned long long*>(ws + WS_MASK_I);
    int myCount = 0;
    #pragma unroll
    for (int cam = 0; cam < NUM_CAMS; ++cam) {
        bool v = false;
        if (inb) {
            const int4 m = *reinterpret_cast<const int4*>(bev + ((size_t)cam * NQ + q) * 4);
            v = (m.x > 0) | (m.y > 0) | (m.z > 0) | (m.w > 0);
        }
        myCount += v ? 1 : 0;
        const unsigned long long bal = __ballot(v);
        if (lane == 0) {
            atomicAdd(&cnt[cam], __popcll(bal));
            if (usePos) wsm[((size_t)cam * NBLK + blk) * 4 + wave] = bal;
        }
    }
    if (inb) out[OFF_CNT + q] = 1.0f / fmaxf((float)myCount, 1.0f);
    __syncthreads();
    if (tid < NUM_CAMS) ws[WS_OFF + tid * NBLK + blk] = cnt[tid];
}

// (157,6) blocks: wave-reduce partials -> exclusive offset + total; valid bits
// come from the stored ballot masks (no bev re-read). Writes idx, len, pos.
__global__ void kBC_indexes(const int* __restrict__ bev, float* __restrict__ out,
                            int* __restrict__ ws, int usePos) {
    const int blk = blockIdx.x;
    const int cam = blockIdx.y;
    const int tid = threadIdx.x;
    const int lane = tid & 63;
    const int wave = tid >> 6;

    const int part = (tid < NBLK) ? ws[WS_OFF + cam * NBLK + tid] : 0;
    int t = part;
    int o = (tid < blk) ? part : 0;
    #pragma unroll
    for (int d = 1; d < 64; d <<= 1) {
        t += __shfl_xor(t, d, 64);
        o += __shfl_xor(o, d, 64);
    }
    __shared__ int sT[4], sO[4], waveSums[4];

    unsigned long long mask;
    if (usePos) {
        const unsigned long long* wsm =
            reinterpret_cast<const unsigned long long*>(ws + WS_MASK_I);
        mask = wsm[((size_t)cam * NBLK + blk) * 4 + wave];
    } else {
        const int q = blk * 256 + tid;
        bool v = false;
        if (q < NQ) {
            const int4 m = *reinterpret_cast<const int4*>(bev + ((size_t)cam * NQ + q) * 4);
            v = (m.x > 0) | (m.y > 0) | (m.z > 0) | (m.w > 0);
        }
        mask = __ballot(v);
    }
    if (lane == 0) { sT[wave] = t; sO[wave] = o; waveSums[wave] = __popcll(mask); }
    __syncthreads();
    const int total    = sT[0] + sT[1] + sT[2] + sT[3];
    const int blockOff = sO[0] + sO[1] + sO[2] + sO[3];

    if (blk == 0 && tid == 0) {
        const int len = total < MAX_LEN ? total : MAX_LEN;
        ws[WS_LEN + cam] = len;
        out[OFF_LEN + cam] = (float)len;
    }

    const int q = blk * 256 + tid;
    if (q < NQ) {
        int waveOff = 0;
        #pragma unroll
        for (int w = 0; w < 4; ++w)
            if (w < wave) waveOff += waveSums[w];
        const bool v     = (mask >> lane) & 1ull;
        const int prefix = __popcll(mask & ((1ull << lane) - 1ull));
        const int vb  = blockOff + waveOff + prefix;
        const int pos = v ? vb : (total + (q - vb));
        if (pos < MAX_LEN) out[OFF_IDX + cam * MAX_LEN + pos] = (float)q;
        if (usePos) ws[WS_POS + cam * NQ + q] = (v && vb < MAX_LEN) ? vb : -1;
    }
}

// Persistent grid-stride: items [0,10000) = q-major multicast (4 q/item, 64
// lanes/q: read the 1KB query row once, scatter to every cam with pos>=0);
// items [10000,25000) = tail rows [len, MAX_LEN) zeroing (4 rows/item).
__global__ void kGatherQ(const float* __restrict__ query, const float* __restrict__ refp,
                         float* __restrict__ out, const int* __restrict__ ws) {
    const int tid   = threadIdx.x;
    const int group = tid >> 6;
    const int lane  = tid & 63;
    for (int item = blockIdx.x; item < QBLOCKS + TAIL_BLOCKS; item += gridDim.x) {
        if (item < QBLOCKS) {
            const int q = item * 4 + group;   // < NQ
            int pos[NUM_CAMS];
            bool any = false;
            #pragma unroll
            for (int cam = 0; cam < NUM_CAMS; ++cam) {
                const int p = ws[WS_POS + cam * NQ + q];
                pos[cam] = p;
                any |= (p >= 0);
            }
            if (!any) continue;

            const float4 vq = *reinterpret_cast<const float4*>(query + (size_t)q * ED + lane * 4);
            f32x2 a; a.x = vq.x; a.y = vq.y;
            f32x2 b; b.x = vq.z; b.y = vq.w;

            #pragma unroll
            for (int cam = 0; cam < NUM_CAMS; ++cam) {
                const int p = pos[cam];
                if (p >= 0) {
                    f32x2* o2 = reinterpret_cast<f32x2*>(out + OFF_Q + ((size_t)cam * MAX_LEN + p) * ED + lane * 4);
                    o2[0] = a;
                    o2[1] = b;
                    if (lane < 4) {
                        const f32x2 r = *reinterpret_cast<const f32x2*>(refp + ((size_t)cam * NQ + q) * 8 + lane * 2);
                        *reinterpret_cast<f32x2*>(out + OFF_REF + ((size_t)cam * MAX_LEN + p) * 8 + lane * 2) = r;
                    }
                }
            }
        } else {
            const int rowId = (item - QBLOCKS) * 4 + group;
            const int cam   = rowId / MAX_LEN;
            const int j     = rowId - cam * MAX_LEN;
            if (j < ws[WS_LEN + cam]) continue;
            const f32x2 z = (f32x2)(0.f);
            f32x2* o2 = reinterpret_cast<f32x2*>(out + OFF_Q + (size_t)rowId * ED + lane * 4);
            o2[0] = z; o2[1] = z;
            if (lane < 4)
                *reinterpret_cast<f32x2*>(out + OFF_REF + (size_t)rowId * 8 + lane * 2) = z;
        }
    }
}

// Fallback row-major gather (+count_norm) if ws too small for masks+pos table.
__global__ void kGather(const float* __restrict__ query, const float* __restrict__ refp,
                        float* __restrict__ out, const int* __restrict__ ws,
                        const int* __restrict__ bev) {
    const int blk = blockIdx.x;
    const int tid = threadIdx.x;
    if (blk >= GATHER_BLOCKS) {
        const int q = (blk - GATHER_BLOCKS) * 256 + tid;
        if (q < NQ) {
            int cnt = 0;
            #pragma unroll
            for (int cam = 0; cam < NUM_CAMS; ++cam) {
                const int4 m = *reinterpret_cast<const int4*>(bev + ((size_t)cam * NQ + q) * 4);
                cnt += ((m.x > 0) | (m.y > 0) | (m.z > 0) | (m.w > 0)) ? 1 : 0;
            }
            out[OFF_CNT + q] = 1.0f / fmaxf((float)cnt, 1.0f);
        }
        return;
    }
    const int rowId = blk * 4 + (tid >> 6);
    const int lane  = tid & 63;
    const int cam   = rowId / MAX_LEN;
    const int j     = rowId - cam * MAX_LEN;
    const int len   = ws[WS_LEN + cam];

    f32x2 a = (f32x2)(0.f), b = (f32x2)(0.f), r0 = (f32x2)(0.f), r1 = (f32x2)(0.f);
    if (j < len) {
        const int idx = (int)out[OFF_IDX + cam * MAX_LEN + j];
        const float4 vq = *reinterpret_cast<const float4*>(query + (size_t)idx * ED + lane * 4);
        a.x = vq.x; a.y = vq.y;
        b.x = vq.z; b.y = vq.w;
        if (lane < 2) {
            const float4 r = *reinterpret_cast<const float4*>(refp + ((size_t)cam * NQ + idx) * 8 + lane * 4);
            r0.x = r.x; r0.y = r.y;
            r1.x = r.z; r1.y = r.w;
        }
    }
    f32x2* o2 = reinterpret_cast<f32x2*>(out + OFF_Q + (size_t)rowId * ED + lane * 4);
    o2[0] = a;
    o2[1] = b;
    if (lane < 2) {
        f32x2* r2 = reinterpret_cast<f32x2*>(out + OFF_REF + (size_t)rowId * 8 + lane * 4);
        r2[0] = r0;
        r2[1] = r1;
    }
}

extern "C" void kernel_launch(void* const* d_in, const int* in_sizes, int n_in,
                              void* d_out, int out_size, void* d_ws, size_t ws_size,
                              hipStream_t stream) {
    const float* query = (const float*)d_in[0];
    const float* refp  = (const float*)d_in[1];
    const int*   bev   = (const int*)d_in[2];
    float* out = (float*)d_out;
    int*   ws  = (int*)d_ws;
    const int usePos = (ws_size >= (size_t)WS_NEED_BYTES) ? 1 : 0;

    kA_counts<<<NBLK, 256, 0, stream>>>(bev, out, ws, usePos);
    kBC_indexes<<<dim3(NBLK, NUM_CAMS), 256, 0, stream>>>(bev, out, ws, usePos);
    if (usePos) {
        kGatherQ<<<GATHER_GRID, 256, 0, stream>>>(query, refp, out, ws);
    } else {
        kGather<<<GATHER_BLOCKS + CNT_BLOCKS, 256, 0, stream>>>(query, refp, out, ws, bev);
    }
}